// Round 1
// baseline (398.526 us; speedup 1.0000x reference)
//
#include <hip/hip_runtime.h>
#include <hip/hip_bf16.h>

#define HW   4096
#define WID  64
#define HEI  64
#define CIN  256
#define OCH  256
#define BAT  4

typedef short bf16x8 __attribute__((ext_vector_type(8)));
typedef float f32x4  __attribute__((ext_vector_type(4)));

// ---------------- w_def transpose to MFMA-friendly tiles ----------------
// w2t[((tap*8 + cb)*256 + o)*32 + ci]  (bf16), c = cb*32+ci, kdim = tap*256+c
__global__ void prep_w2(const float* __restrict__ w_def,
                        __hip_bfloat16* __restrict__ w2t) {
    int idx = blockIdx.x * 256 + threadIdx.x;          // 0..589823
    int ci  = idx & 31;
    int o   = (idx >> 5) & 255;
    int cb  = (idx >> 13) & 7;
    int tap = idx >> 16;
    int c   = cb * 32 + ci;
    float v = w_def[(o * CIN + c) * 9 + tap];
    w2t[idx] = __float2bfloat16(v);
}

// ---------------- offset conv: init with bias, then c-split accumulate ----
__global__ void off_init(float* __restrict__ off, const float* __restrict__ b_off) {
    int idx = blockIdx.x * 256 + threadIdx.x;          // B*18*HW = 294912
    int j = (idx >> 12) % 18;
    off[idx] = b_off[j];
}

__global__ __launch_bounds__(64) void off_conv(const float* __restrict__ x,
                                               const float* __restrict__ w_off,
                                               float* __restrict__ off) {
    // grid = 4cc * 64h * 4b = 1024 blocks of 64 threads (one per w)
    int blk = blockIdx.x;
    int cc  = blk & 3;
    int h   = (blk >> 2) & 63;
    int b   = blk >> 8;
    int w   = threadIdx.x;

    float acc[18];
#pragma unroll
    for (int j = 0; j < 18; ++j) acc[j] = 0.f;

    const float* xb = x + b * CIN * HW;
    for (int c = cc * 64; c < cc * 64 + 64; ++c) {
        const float* xp = xb + c * HW;
#pragma unroll
        for (int tap = 0; tap < 9; ++tap) {
            int yy = h + tap / 3 - 1;
            int xx = w + tap % 3 - 1;
            float xv = 0.f;
            if ((unsigned)yy < 64u && (unsigned)xx < 64u) xv = xp[yy * 64 + xx];
#pragma unroll
            for (int j = 0; j < 18; ++j)
                acc[j] = fmaf(xv, w_off[j * 2304 + c * 9 + tap], acc[j]);
        }
    }
    int base = (b * 18) * HW + h * 64 + w;
#pragma unroll
    for (int j = 0; j < 18; ++j)
        atomicAdd(&off[base + j * HW], acc[j]);
}

// ---------------- main deformable conv: implicit GEMM, bf16 MFMA ---------
// M-tile = 64 positions (one image row: fixed b,h), N = 256, K = 9 taps * 256 c
__global__ __launch_bounds__(256) void main_conv(const float* __restrict__ x,
                                                 const float* __restrict__ off,
                                                 const __hip_bfloat16* __restrict__ w2t,
                                                 float* __restrict__ out) {
    int b = blockIdx.x >> 6;
    int h = blockIdx.x & 63;
    int t = threadIdx.x;
    int pos  = t & 63;   // w coordinate handled in gather phase
    int wave = t >> 6;   // 0..3 ; also c-subgroup in gather phase
    int lane = t & 63;
    int mrow = lane & 15;
    int quad = lane >> 4;

    __shared__ int   sA[4][64];   // per-pos clamped plane offsets (4 corners)
    __shared__ float sW[4][64];   // per-pos bilinear*valid weights
    __shared__ __align__(16) unsigned short ldsA[64][40];   // 64 pos x (32k + 8 pad)
    __shared__ __align__(16) unsigned short ldsB[256][40];  // 256 o  x (32k + 8 pad)

    f32x4 acc[4][4];
#pragma unroll
    for (int m = 0; m < 4; ++m)
#pragma unroll
        for (int n = 0; n < 4; ++n) acc[m][n] = {0.f, 0.f, 0.f, 0.f};

    const float* xb = x + b * CIN * HW;
    const unsigned short* w2u = (const unsigned short*)w2t;

    for (int tap = 0; tap < 9; ++tap) {
        // ---- per-tap coords: threads 0..63, one per position ----
        if (t < 64) {
            int w = t;
            float oy = off[(b * 18 + 2 * tap) * HW + h * 64 + w];
            float ox = off[(b * 18 + 2 * tap + 1) * HW + h * 64 + w];
            float py = oy + (float)(tap / 3 + h - 1);
            float px = ox + (float)(tap % 3 + w - 1);
            float y0f = floorf(py), x0f = floorf(px);
            float wy1 = py - y0f, wx1 = px - x0f;
            float wy0 = 1.f - wy1, wx0 = 1.f - wx1;
            bool vy0 = (y0f >= 0.f) && (y0f <= 63.f);
            bool vy1 = (y0f >= -1.f) && (y0f <= 62.f);
            bool vx0 = (x0f >= 0.f) && (x0f <= 63.f);
            bool vx1 = (x0f >= -1.f) && (x0f <= 62.f);
            int iy0 = min(max((int)y0f, 0), 63);
            int iy1 = min(max((int)y0f + 1, 0), 63);
            int ix0 = min(max((int)x0f, 0), 63);
            int ix1 = min(max((int)x0f + 1, 0), 63);
            sA[0][w] = iy0 * 64 + ix0;
            sA[1][w] = iy0 * 64 + ix1;
            sA[2][w] = iy1 * 64 + ix0;
            sA[3][w] = iy1 * 64 + ix1;
            sW[0][w] = wy0 * wx0 * (float)(vy0 && vx0);
            sW[1][w] = wy0 * wx1 * (float)(vy0 && vx1);
            sW[2][w] = wy1 * wx0 * (float)(vy1 && vx0);
            sW[3][w] = wy1 * wx1 * (float)(vy1 && vx1);
        }
        __syncthreads();
        int   a0 = sA[0][pos], a1 = sA[1][pos], a2 = sA[2][pos], a3 = sA[3][pos];
        float f0 = sW[0][pos], f1 = sW[1][pos], f2 = sW[2][pos], f3 = sW[3][pos];

        for (int cb = 0; cb < 8; ++cb) {
            // ---- stage A: gather+bilinear, 8 channels per thread ----
            const float* xp = xb + (cb * 32 + wave * 8) * HW;
            unsigned short av[8];
#pragma unroll
            for (int i = 0; i < 8; ++i) {
                const float* p = xp + i * HW;
                float v = f0 * p[a0] + f1 * p[a1] + f2 * p[a2] + f3 * p[a3];
                __hip_bfloat16 hb = __float2bfloat16(v);
                av[i] = reinterpret_cast<unsigned short&>(hb);
            }
            *(uint4*)&ldsA[pos][wave * 8] = *(const uint4*)av;

            // ---- stage B: row o = t, contiguous 64B from w2t ----
            const uint4* wsrc = (const uint4*)(w2u + (((size_t)tap * 8 + cb) * 256 + t) * 32);
            uint4 b0 = wsrc[0], b1 = wsrc[1], b2 = wsrc[2], b3 = wsrc[3];
            *(uint4*)&ldsB[t][0]  = b0;
            *(uint4*)&ldsB[t][8]  = b1;
            *(uint4*)&ldsB[t][16] = b2;
            *(uint4*)&ldsB[t][24] = b3;
            __syncthreads();

            // ---- MFMA: wave covers m 0..3 x n-tiles wave*4..+3 ----
            bf16x8 afrag[4], bfrag[4];
#pragma unroll
            for (int m = 0; m < 4; ++m)
                afrag[m] = *(const bf16x8*)&ldsA[m * 16 + mrow][quad * 8];
#pragma unroll
            for (int n = 0; n < 4; ++n)
                bfrag[n] = *(const bf16x8*)&ldsB[wave * 64 + n * 16 + mrow][quad * 8];
#pragma unroll
            for (int m = 0; m < 4; ++m)
#pragma unroll
                for (int n = 0; n < 4; ++n)
                    acc[m][n] = __builtin_amdgcn_mfma_f32_16x16x32_bf16(
                        afrag[m], bfrag[n], acc[m][n], 0, 0, 0);
            __syncthreads();
        }
    }

    // ---- epilogue: C layout col=lane&15 (o), row=quad*4+reg (pos) ----
#pragma unroll
    for (int m = 0; m < 4; ++m)
#pragma unroll
        for (int n = 0; n < 4; ++n) {
            int o = wave * 64 + n * 16 + mrow;
            int p = m * 16 + quad * 4;
            float* dst = out + ((size_t)(b * OCH + o)) * HW + h * 64 + p;
            *(f32x4*)dst = acc[m][n];
        }
}

// ---------------- BN stats + apply ----------------
__global__ __launch_bounds__(256) void bn_stats(const float* __restrict__ out,
                                                const float* __restrict__ gamma,
                                                float* __restrict__ mean_s,
                                                float* __restrict__ scale_s) {
    int o = blockIdx.x;
    float s = 0.f, s2 = 0.f;
    for (int b = 0; b < BAT; ++b) {
        const float* p = out + ((size_t)(b * OCH + o)) * HW;
        for (int i = threadIdx.x; i < HW; i += 256) {
            float v = p[i];
            s += v;
            s2 += v * v;
        }
    }
#pragma unroll
    for (int d = 32; d; d >>= 1) {
        s  += __shfl_down(s, d);
        s2 += __shfl_down(s2, d);
    }
    __shared__ float ws1[4], ws2[4];
    int lane = threadIdx.x & 63, wv = threadIdx.x >> 6;
    if (lane == 0) { ws1[wv] = s; ws2[wv] = s2; }
    __syncthreads();
    if (threadIdx.x == 0) {
        float S  = ws1[0] + ws1[1] + ws1[2] + ws1[3];
        float S2 = ws2[0] + ws2[1] + ws2[2] + ws2[3];
        float m  = S / 16384.f;
        float var = S2 / 16384.f - m * m;
        mean_s[o]  = m;
        scale_s[o] = gamma[o] * rsqrtf(var + 1e-5f);
    }
}

__global__ void bn_apply(float* __restrict__ out,
                         const float* __restrict__ mean_s,
                         const float* __restrict__ scale_s,
                         const float* __restrict__ beta) {
    int idx4 = blockIdx.x * 256 + threadIdx.x;       // 1,048,576 float4s
    int o = (idx4 >> 10) & 255;
    float4 v = ((const float4*)out)[idx4];
    float mu = mean_s[o], sc = scale_s[o], be = beta[o];
    v.x = fmaxf((v.x - mu) * sc + be, 0.f);
    v.y = fmaxf((v.y - mu) * sc + be, 0.f);
    v.z = fmaxf((v.z - mu) * sc + be, 0.f);
    v.w = fmaxf((v.w - mu) * sc + be, 0.f);
    ((float4*)out)[idx4] = v;
}

extern "C" void kernel_launch(void* const* d_in, const int* in_sizes, int n_in,
                              void* d_out, int out_size, void* d_ws, size_t ws_size,
                              hipStream_t stream) {
    const float* x     = (const float*)d_in[0];
    const float* w_off = (const float*)d_in[1];
    const float* b_off = (const float*)d_in[2];
    const float* w_def = (const float*)d_in[3];
    const float* gamma = (const float*)d_in[4];
    const float* beta  = (const float*)d_in[5];
    float* out = (float*)d_out;

    char* ws = (char*)d_ws;
    float* off            = (float*)ws;                       // 1,179,648 B
    __hip_bfloat16* w2t   = (__hip_bfloat16*)(ws + 1179648);  // 1,179,648 B
    float* mean_s         = (float*)(ws + 2359296);           // 1 KiB
    float* scale_s        = (float*)(ws + 2359296 + 1024);    // 1 KiB

    prep_w2 <<<589824 / 256, 256, 0, stream>>>(w_def, w2t);
    off_init<<<294912 / 256, 256, 0, stream>>>(off, b_off);
    off_conv<<<1024, 64, 0, stream>>>(x, w_off, off);
    main_conv<<<256, 256, 0, stream>>>(x, off, w2t, out);
    bn_stats<<<256, 256, 0, stream>>>(out, gamma, mean_s, scale_s);
    bn_apply<<<4194304 / 1024, 256, 0, stream>>>(out, mean_s, scale_s, beta);
}

// Round 2
// 297.869 us; speedup vs baseline: 1.3379x; 1.3379x over previous
//
#include <hip/hip_runtime.h>
#include <hip/hip_bf16.h>

typedef unsigned int  uint;
typedef unsigned short ushort;
typedef short bf16x8 __attribute__((ext_vector_type(8)));
typedef float f32x4  __attribute__((ext_vector_type(4)));

#define HW   4096
#define KD   2304   // 9 taps * 256 c

__device__ __forceinline__ void load_lds16(const void* g, void* l) {
    __builtin_amdgcn_global_load_lds((const __attribute__((address_space(1))) void*)g,
                                     (__attribute__((address_space(3))) void*)l, 16, 0, 0);
}
__device__ __forceinline__ float blo(uint u) { return __uint_as_float(u << 16); }
__device__ __forceinline__ float bhi(uint u) { return __uint_as_float(u & 0xffff0000u); }
__device__ __forceinline__ uint pack2(float e, float o) {
    __hip_bfloat16 he = __float2bfloat16(e), ho = __float2bfloat16(o);
    return (uint)(*(ushort*)&he) | ((uint)(*(ushort*)&ho) << 16);
}

// ---- x -> bf16 channel-pair-interleaved: x2[(b*128+cp)*4096 + a] = {c=2cp, c=2cp+1}
__global__ void prep_x2(const float* __restrict__ x, uint* __restrict__ x2) {
    int idx = blockIdx.x * 256 + threadIdx.x;      // 2,097,152
    int a  = idx & 4095;
    int cp = (idx >> 12) & 127;
    int b  = idx >> 19;
    const float* p = x + ((size_t)(b * 256 + 2 * cp)) * HW + a;
    x2[idx] = pack2(p[0], p[HW]);
}

// ---- w_def -> Bt[o*2304 + tap*256 + c]
__global__ void prep_bt(const float* __restrict__ w_def, ushort* __restrict__ bt) {
    int idx = blockIdx.x * 256 + threadIdx.x;      // 589,824
    int c   = idx & 255;
    int tap = (idx >> 8) % 9;
    int o   = idx / KD;
    __hip_bfloat16 h = __float2bfloat16(w_def[(o * 256 + c) * 9 + tap]);
    bt[idx] = *(ushort*)&h;
}

// ---- w_off -> Bt0[j*2304 + tap*256 + c], rows 18..31 zero
__global__ void prep_bt0(const float* __restrict__ w_off, ushort* __restrict__ bt0) {
    int idx = blockIdx.x * 256 + threadIdx.x;      // 73,728
    int c   = idx & 255;
    int tap = (idx >> 8) % 9;
    int j   = idx / KD;
    float v = (j < 18) ? w_off[(j * 256 + c) * 9 + tap] : 0.f;
    __hip_bfloat16 h = __float2bfloat16(v);
    bt0[idx] = *(ushort*)&h;
}

// ---- undeformed im2col: A0[pos*2304 + tap*256 + c]
__global__ __launch_bounds__(256) void build_a0(const uint* __restrict__ x2,
                                                ushort* __restrict__ a0m) {
    int bh = blockIdx.x, tap = blockIdx.y;
    int b = bh >> 6, h = bh & 63;
    int w = threadIdx.x & 63, cg = threadIdx.x >> 6;
    int yy = h + tap / 3 - 1, xx = w + tap % 3 - 1;
    bool ok = (unsigned)yy < 64u && (unsigned)xx < 64u;
    int a = ok ? yy * 64 + xx : 0;
    const uint* xp = x2 + ((size_t)(b * 128 + cg * 32)) * HW + a;
    ushort* row = a0m + ((size_t)(bh * 64 + w)) * KD + tap * 256 + cg * 64;
    for (int j0 = 0; j0 < 32; j0 += 4) {
        uint q[4];
#pragma unroll
        for (int u = 0; u < 4; ++u) {
            uint v = xp[(size_t)(j0 + u) * HW];
            q[u] = ok ? v : 0u;
        }
        uint4 qq = {q[0], q[1], q[2], q[3]};
        *(uint4*)(row + 2 * j0) = qq;
    }
}

// ---- deformed gather: vals[pos*2304 + tap*256 + c]
__global__ __launch_bounds__(256) void gather_vals(const uint* __restrict__ x2,
                                                   const float* __restrict__ off,
                                                   ushort* __restrict__ vals) {
    int bh = blockIdx.x, tap = blockIdx.y;
    int b = bh >> 6, h = bh & 63;
    int w = threadIdx.x & 63, cg = threadIdx.x >> 6;
    int hw = h * 64 + w;
    float oy = off[((size_t)(b * 32 + 2 * tap)) * HW + hw];
    float ox = off[((size_t)(b * 32 + 2 * tap + 1)) * HW + hw];
    float py = oy + (float)(tap / 3 + h - 1);
    float px = ox + (float)(tap % 3 + w - 1);
    float y0f = floorf(py), x0f = floorf(px);
    float wy1 = py - y0f, wx1 = px - x0f;
    float wy0 = 1.f - wy1, wx0 = 1.f - wx1;
    bool vy0 = (y0f >= 0.f) && (y0f <= 63.f);
    bool vy1 = (y0f >= -1.f) && (y0f <= 62.f);
    bool vx0 = (x0f >= 0.f) && (x0f <= 63.f);
    bool vx1 = (x0f >= -1.f) && (x0f <= 62.f);
    int iy0 = min(max((int)y0f, 0), 63),     iy1 = min(max((int)y0f + 1, 0), 63);
    int ix0 = min(max((int)x0f, 0), 63),     ix1 = min(max((int)x0f + 1, 0), 63);
    int a0 = iy0 * 64 + ix0, a1 = iy0 * 64 + ix1, a2 = iy1 * 64 + ix0, a3 = iy1 * 64 + ix1;
    float f0 = wy0 * wx0 * (float)(vy0 && vx0);
    float f1 = wy0 * wx1 * (float)(vy0 && vx1);
    float f2 = wy1 * wx0 * (float)(vy1 && vx0);
    float f3 = wy1 * wx1 * (float)(vy1 && vx1);

    const uint* xp = x2 + ((size_t)(b * 128 + cg * 32)) * HW;
    ushort* row = vals + ((size_t)(bh * 64 + w)) * KD + tap * 256 + cg * 64;
    for (int j0 = 0; j0 < 32; j0 += 4) {
        uint q[4];
#pragma unroll
        for (int u = 0; u < 4; ++u) {
            const uint* p = xp + (size_t)(j0 + u) * HW;
            uint u0 = p[a0], u1 = p[a1], u2 = p[a2], u3 = p[a3];
            float e = f0 * blo(u0) + f1 * blo(u1) + f2 * blo(u2) + f3 * blo(u3);
            float o = f0 * bhi(u0) + f1 * bhi(u1) + f2 * bhi(u2) + f3 * bhi(u3);
            q[u] = pack2(e, o);
        }
        uint4 qq = {q[0], q[1], q[2], q[3]};
        *(uint4*)(row + 2 * j0) = qq;
    }
}

// ---- main GEMM: C[pos][o] = vals[pos][k] . Bt[o][k], BM=64 BN=128 BK=64
__global__ __launch_bounds__(256) void gemm_main(const ushort* __restrict__ A,
                                                 const ushort* __restrict__ Bt,
                                                 float* __restrict__ out) {
    int posBase = blockIdx.x * 64;
    int oBase   = blockIdx.y * 128;
    int t = threadIdx.x, wv = t >> 6, lane = t & 63;
    int mrow = lane & 15, quad = lane >> 4;
    int lrow = lane >> 3, lcc = lane & 7;

    __shared__ ushort lA[64 * 64];
    __shared__ ushort lB[128 * 64];

    f32x4 acc[4][2];
#pragma unroll
    for (int m = 0; m < 4; ++m)
#pragma unroll
        for (int n = 0; n < 2; ++n) acc[m][n] = {0.f, 0.f, 0.f, 0.f};

    for (int k0 = 0; k0 < KD; k0 += 64) {
#pragma unroll
        for (int s = 0; s < 2; ++s) {            // A: 8KB, 2 instr/wave
            int q = wv * 2 + s;
            int r = q * 8 + lrow;
            int gcc = lcc ^ (r & 7);
            const ushort* gp = A + (size_t)(posBase + r) * KD + k0 + gcc * 8;
            load_lds16(gp, (char*)lA + q * 1024);
        }
#pragma unroll
        for (int s = 0; s < 4; ++s) {            // B: 16KB, 4 instr/wave
            int q = wv * 4 + s;
            int r = q * 8 + lrow;
            int gcc = lcc ^ (r & 7);
            const ushort* gp = Bt + (size_t)(oBase + r) * KD + k0 + gcc * 8;
            load_lds16(gp, (char*)lB + q * 1024);
        }
        __syncthreads();
#pragma unroll
        for (int kb = 0; kb < 2; ++kb) {
            bf16x8 af[4], bf[2];
#pragma unroll
            for (int m = 0; m < 4; ++m) {
                int r = m * 16 + mrow;
                af[m] = *(const bf16x8*)&lA[r * 64 + (((kb * 4 + quad) ^ (r & 7)) * 8)];
            }
#pragma unroll
            for (int n = 0; n < 2; ++n) {
                int r = wv * 32 + n * 16 + mrow;
                bf[n] = *(const bf16x8*)&lB[r * 64 + (((kb * 4 + quad) ^ (r & 7)) * 8)];
            }
#pragma unroll
            for (int m = 0; m < 4; ++m)
#pragma unroll
                for (int n = 0; n < 2; ++n)
                    acc[m][n] = __builtin_amdgcn_mfma_f32_16x16x32_bf16(af[m], bf[n], acc[m][n], 0, 0, 0);
        }
        __syncthreads();
    }
#pragma unroll
    for (int m = 0; m < 4; ++m)
#pragma unroll
        for (int n = 0; n < 2; ++n) {
            int o   = oBase + wv * 32 + n * 16 + mrow;
            int pos = posBase + m * 16 + quad * 4;
            int b = pos >> 12, hw = pos & 4095;
            *(f32x4*)(out + ((size_t)(b * 256 + o)) * HW + hw) = acc[m][n];
        }
}

// ---- offset GEMM: off[b][32][hw] = A0 . Bt0 + bias, BM=64 BN=32 BK=64
__global__ __launch_bounds__(256) void gemm_off(const ushort* __restrict__ A,
                                                const ushort* __restrict__ Bt0,
                                                const float* __restrict__ b_off,
                                                float* __restrict__ off) {
    int posBase = blockIdx.x * 64;
    int t = threadIdx.x, wv = t >> 6, lane = t & 63;
    int mrow = lane & 15, quad = lane >> 4;
    int lrow = lane >> 3, lcc = lane & 7;

    __shared__ ushort lA[64 * 64];
    __shared__ ushort lB[32 * 64];

    f32x4 acc[2];
    acc[0] = {0.f, 0.f, 0.f, 0.f};
    acc[1] = {0.f, 0.f, 0.f, 0.f};

    for (int k0 = 0; k0 < KD; k0 += 64) {
#pragma unroll
        for (int s = 0; s < 2; ++s) {
            int q = wv * 2 + s;
            int r = q * 8 + lrow;
            int gcc = lcc ^ (r & 7);
            const ushort* gp = A + (size_t)(posBase + r) * KD + k0 + gcc * 8;
            load_lds16(gp, (char*)lA + q * 1024);
        }
        {
            int r = wv * 8 + lrow;
            int gcc = lcc ^ (r & 7);
            const ushort* gp = Bt0 + (size_t)r * KD + k0 + gcc * 8;
            load_lds16(gp, (char*)lB + wv * 1024);
        }
        __syncthreads();
#pragma unroll
        for (int kb = 0; kb < 2; ++kb) {
            int ra = wv * 16 + mrow;
            bf16x8 af = *(const bf16x8*)&lA[ra * 64 + (((kb * 4 + quad) ^ (ra & 7)) * 8)];
#pragma unroll
            for (int n = 0; n < 2; ++n) {
                int rb = n * 16 + mrow;
                bf16x8 bf = *(const bf16x8*)&lB[rb * 64 + (((kb * 4 + quad) ^ (rb & 7)) * 8)];
                acc[n] = __builtin_amdgcn_mfma_f32_16x16x32_bf16(af, bf, acc[n], 0, 0, 0);
            }
        }
        __syncthreads();
    }
#pragma unroll
    for (int n = 0; n < 2; ++n) {
        int o   = n * 16 + mrow;
        int pos = posBase + wv * 16 + quad * 4;
        int b = pos >> 12, hw = pos & 4095;
        float bias = (o < 18) ? b_off[o] : 0.f;
        f32x4 v = acc[n];
        v.x += bias; v.y += bias; v.z += bias; v.w += bias;
        *(f32x4*)(off + ((size_t)(b * 32 + o)) * HW + hw) = v;
    }
}

// ---- BN stats + apply ----
__global__ __launch_bounds__(256) void bn_stats(const float* __restrict__ out,
                                                const float* __restrict__ gamma,
                                                float* __restrict__ mean_s,
                                                float* __restrict__ scale_s) {
    int o = blockIdx.x;
    float s = 0.f, s2 = 0.f;
    for (int b = 0; b < 4; ++b) {
        const float4* p = (const float4*)(out + ((size_t)(b * 256 + o)) * HW);
        for (int i = threadIdx.x; i < HW / 4; i += 256) {
            float4 v = p[i];
            s  += v.x + v.y + v.z + v.w;
            s2 += v.x * v.x + v.y * v.y + v.z * v.z + v.w * v.w;
        }
    }
#pragma unroll
    for (int d = 32; d; d >>= 1) {
        s  += __shfl_down(s, d);
        s2 += __shfl_down(s2, d);
    }
    __shared__ float ws1[4], ws2[4];
    int lane = threadIdx.x & 63, wv = threadIdx.x >> 6;
    if (lane == 0) { ws1[wv] = s; ws2[wv] = s2; }
    __syncthreads();
    if (threadIdx.x == 0) {
        float S  = ws1[0] + ws1[1] + ws1[2] + ws1[3];
        float S2 = ws2[0] + ws2[1] + ws2[2] + ws2[3];
        float m  = S / 16384.f;
        float var = S2 / 16384.f - m * m;
        mean_s[o]  = m;
        scale_s[o] = gamma[o] * rsqrtf(var + 1e-5f);
    }
}

__global__ void bn_apply(float* __restrict__ out,
                         const float* __restrict__ mean_s,
                         const float* __restrict__ scale_s,
                         const float* __restrict__ beta) {
    int idx4 = blockIdx.x * 256 + threadIdx.x;   // 1,048,576 float4s
    int o = (idx4 >> 10) & 255;
    float4 v = ((const float4*)out)[idx4];
    float mu = mean_s[o], sc = scale_s[o], be = beta[o];
    v.x = fmaxf((v.x - mu) * sc + be, 0.f);
    v.y = fmaxf((v.y - mu) * sc + be, 0.f);
    v.z = fmaxf((v.z - mu) * sc + be, 0.f);
    v.w = fmaxf((v.w - mu) * sc + be, 0.f);
    ((float4*)out)[idx4] = v;
}

extern "C" void kernel_launch(void* const* d_in, const int* in_sizes, int n_in,
                              void* d_out, int out_size, void* d_ws, size_t ws_size,
                              hipStream_t stream) {
    const float* x     = (const float*)d_in[0];
    const float* w_off = (const float*)d_in[1];
    const float* b_off = (const float*)d_in[2];
    const float* w_def = (const float*)d_in[3];
    const float* gamma = (const float*)d_in[4];
    const float* beta  = (const float*)d_in[5];
    float* out = (float*)d_out;

    char* ws = (char*)d_ws;
    uint*   x2    = (uint*)ws;                          // 8,388,608 B
    ushort* vals  = (ushort*)(ws + 8388608);            // 75,497,472 B (A0 then vals)
    ushort* bt    = (ushort*)(ws + 83886080);           // 1,179,648 B
    ushort* bt0   = (ushort*)(ws + 85065728);           // 147,456 B
    float*  off   = (float*)(ws + 85213184);            // 2,097,152 B
    float*  mean_s  = (float*)(ws + 87310336);
    float*  scale_s = (float*)(ws + 87311360);

    prep_x2 <<<8192, 256, 0, stream>>>(x, x2);
    prep_bt <<<2304, 256, 0, stream>>>(w_def, bt);
    prep_bt0<<<288,  256, 0, stream>>>(w_off, bt0);
    build_a0<<<dim3(256, 9), 256, 0, stream>>>(x2, vals);
    gemm_off<<<256, 256, 0, stream>>>(vals, bt0, b_off, off);
    gather_vals<<<dim3(256, 9), 256, 0, stream>>>(x2, off, vals);
    gemm_main<<<dim3(256, 2), 256, 0, stream>>>(vals, bt, out);
    bn_stats<<<256, 256, 0, stream>>>(out, gamma, mean_s, scale_s);
    bn_apply<<<4096, 256, 0, stream>>>(out, mean_s, scale_s, beta);
}

// Round 3
// 196.491 us; speedup vs baseline: 2.0282x; 1.5159x over previous
//
#include <hip/hip_runtime.h>
#include <hip/hip_bf16.h>

typedef unsigned int  uint;
typedef unsigned short ushort;
typedef short bf16x8 __attribute__((ext_vector_type(8)));
typedef float f32x4  __attribute__((ext_vector_type(4)));

#define HW   4096
#define KD   2304   // 9 taps * 256 c

__device__ __forceinline__ void load_lds16(const void* g, void* l) {
    __builtin_amdgcn_global_load_lds((const __attribute__((address_space(1))) void*)g,
                                     (__attribute__((address_space(3))) void*)l, 16, 0, 0);
}
__device__ __forceinline__ float blo(uint u) { return __uint_as_float(u << 16); }
__device__ __forceinline__ float bhi(uint u) { return __uint_as_float(u & 0xffff0000u); }
__device__ __forceinline__ uint pack2(float e, float o) {
    __hip_bfloat16 he = __float2bfloat16(e), ho = __float2bfloat16(o);
    return (uint)(*(ushort*)&he) | ((uint)(*(ushort*)&ho) << 16);
}

// ---- x -> bf16 channel-pair-interleaved: x2[(b*128+cp)*4096 + a] = {c=2cp, c=2cp+1}
__global__ void prep_x2(const float* __restrict__ x, uint* __restrict__ x2) {
    int idx = blockIdx.x * 256 + threadIdx.x;      // 2,097,152
    int a  = idx & 4095;
    int cp = (idx >> 12) & 127;
    int b  = idx >> 19;
    const float* p = x + ((size_t)(b * 256 + 2 * cp)) * HW + a;
    x2[idx] = pack2(p[0], p[HW]);
}

// ---- w_def -> Bt[o*2304 + tap*256 + c]
__global__ void prep_bt(const float* __restrict__ w_def, ushort* __restrict__ bt) {
    int idx = blockIdx.x * 256 + threadIdx.x;      // 589,824
    int c   = idx & 255;
    int tap = (idx >> 8) % 9;
    int o   = idx / KD;
    __hip_bfloat16 h = __float2bfloat16(w_def[(o * 256 + c) * 9 + tap]);
    bt[idx] = *(ushort*)&h;
}

// ---- w_off -> Bt0[j*2304 + tap*256 + c], rows 18..31 zero
__global__ void prep_bt0(const float* __restrict__ w_off, ushort* __restrict__ bt0) {
    int idx = blockIdx.x * 256 + threadIdx.x;      // 73,728
    int c   = idx & 255;
    int tap = (idx >> 8) % 9;
    int j   = idx / KD;
    float v = (j < 18) ? w_off[(j * 256 + c) * 9 + tap] : 0.f;
    __hip_bfloat16 h = __float2bfloat16(v);
    bt0[idx] = *(ushort*)&h;
}

// ---- fused offset conv: direct implicit GEMM from x2, no im2col ----
// off[b][32][hw] for one (b,h) row per block. BM=64(w) BN=32(j) K=2304.
__global__ __launch_bounds__(256) void gemm_off(const uint* __restrict__ x2,
                                                const ushort* __restrict__ bt0,
                                                const float* __restrict__ b_off,
                                                float* __restrict__ off) {
    int b = blockIdx.x >> 6, h = blockIdx.x & 63;
    int t = threadIdx.x, wv = t >> 6, lane = t & 63;
    int mrow = lane & 15, quad = lane >> 4;

    __shared__ uint   lX[3 * 32 * 64];     // [dy][cp][w] dwords, 24 KB
    __shared__ ushort lB[32 * 576];        // [o][72 chunks of 8, XOR-swizzled], 36 KB

    f32x4 acc[2];
    acc[0] = {0.f, 0.f, 0.f, 0.f};
    acc[1] = {0.f, 0.f, 0.f, 0.f};

    for (int cb = 0; cb < 4; ++cb) {
        // stage X: 24 wave-chunks of 1024B; lane l -> lX dword q*256 + l*4
#pragma unroll
        for (int s = 0; s < 6; ++s) {
            int q  = s * 4 + wv;            // 0..23, wave-uniform
            int dy = q >> 3;                // wave-uniform
            int y  = h + dy - 1;
            int dl = (q & 7) * 256 + lane * 4;   // dword in dy-slab
            int cp = dl >> 6, w4 = dl & 63;
            uint* dst = &lX[q * 256 + lane * 4];
            if ((unsigned)y < 64u) {
                const uint* src = x2 + ((size_t)(b * 128 + cb * 32 + cp)) * HW + y * 64 + w4;
                load_lds16(src, &lX[q * 256]);   // base wave-uniform; lane scatter = +l*16B
            } else {
                uint4 z = {0u, 0u, 0u, 0u};
                *(uint4*)dst = z;
            }
        }
        // stage B: 36 wave-chunks; element e = q*512 + l*8 (ushort)
#pragma unroll
        for (int s = 0; s < 9; ++s) {
            int q = s * 4 + wv;             // 0..35, wave-uniform
            int e = q * 512 + lane * 8;
            int o  = e / 576;
            int r  = e - o * 576;
            int chp = r >> 3;               // stored chunk position 0..71
            int ch  = chp ^ (o & 7);        // actual chunk (XOR within low 3 bits)
            int tap = ch >> 3, k8 = ch & 7;
            const ushort* src = bt0 + (size_t)o * KD + tap * 256 + cb * 64 + k8 * 8;
            load_lds16(src, &lB[q * 512]);  // base wave-uniform
        }
        __syncthreads();

#pragma unroll
        for (int tap = 0; tap < 9; ++tap) {
            int dy = tap / 3, dx = tap % 3;
            int xx = wv * 16 + mrow + dx - 1;
            bool vx = (unsigned)xx < 64u;
#pragma unroll
            for (int kb = 0; kb < 2; ++kb) {
                int cp0 = kb * 16 + quad * 4;
                uint ad[4];
#pragma unroll
                for (int i = 0; i < 4; ++i)
                    ad[i] = vx ? lX[(dy * 32 + cp0 + i) * 64 + xx] : 0u;
                bf16x8 af = *(bf16x8*)ad;
#pragma unroll
                for (int n = 0; n < 2; ++n) {
                    int o = n * 16 + mrow;
                    int chs = (tap * 8 + (((kb * 4 + quad)) ^ (o & 7)));
                    bf16x8 bf = *(const bf16x8*)&lB[o * 576 + chs * 8];
                    acc[n] = __builtin_amdgcn_mfma_f32_16x16x32_bf16(af, bf, acc[n], 0, 0, 0);
                }
            }
        }
        __syncthreads();
    }
#pragma unroll
    for (int n = 0; n < 2; ++n) {
        int o = n * 16 + mrow;
        float bias = (o < 18) ? b_off[o] : 0.f;
        f32x4 v = acc[n];
        v.x += bias; v.y += bias; v.z += bias; v.w += bias;
        int wpos = wv * 16 + quad * 4;
        *(f32x4*)(off + ((size_t)(b * 32 + o)) * HW + h * 64 + wpos) = v;
    }
}

// ---- deformed gather v2: XCD-batch swizzle + LDS transpose + full-line writes
__global__ __launch_bounds__(256) void gather_vals(const uint* __restrict__ x2,
                                                   const float* __restrict__ off,
                                                   ushort* __restrict__ vals) {
    int id  = blockIdx.x;                 // 2304 blocks
    int xcd = id & 7, j = id >> 3;
    int b   = xcd >> 1, hh = xcd & 1;
    int tap = j >> 5,  h  = hh * 32 + (j & 31);
    int t = threadIdx.x;
    int w = t & 63, cg = t >> 6;
    int hw = h * 64 + w;

    float oy = off[((size_t)(b * 32 + 2 * tap)) * HW + hw];
    float ox = off[((size_t)(b * 32 + 2 * tap + 1)) * HW + hw];
    float py = oy + (float)(tap / 3 + h - 1);
    float px = ox + (float)(tap % 3 + w - 1);
    float y0f = floorf(py), x0f = floorf(px);
    float wy1 = py - y0f, wx1 = px - x0f;
    float wy0 = 1.f - wy1, wx0 = 1.f - wx1;
    bool vy0 = (y0f >= 0.f) && (y0f <= 63.f);
    bool vy1 = (y0f >= -1.f) && (y0f <= 62.f);
    bool vx0 = (x0f >= 0.f) && (x0f <= 63.f);
    bool vx1 = (x0f >= -1.f) && (x0f <= 62.f);
    int iy0 = min(max((int)y0f, 0), 63),     iy1 = min(max((int)y0f + 1, 0), 63);
    int ix0 = min(max((int)x0f, 0), 63),     ix1 = min(max((int)x0f + 1, 0), 63);
    int a0 = iy0 * 64 + ix0, a1 = iy0 * 64 + ix1, a2 = iy1 * 64 + ix0, a3 = iy1 * 64 + ix1;
    float f0 = wy0 * wx0 * (float)(vy0 && vx0);
    float f1 = wy0 * wx1 * (float)(vy0 && vx1);
    float f2 = wy1 * wx0 * (float)(vy1 && vx0);
    float f3 = wy1 * wx1 * (float)(vy1 && vx1);

    const uint* xp = x2 + ((size_t)(b * 128 + cg * 32)) * HW;
    uint res[32];
#pragma unroll
    for (int g = 0; g < 4; ++g) {
#pragma unroll
        for (int i = 0; i < 8; ++i) {
            int k = g * 8 + i;
            const uint* p = xp + (size_t)k * HW;
            uint u0 = p[a0], u1 = p[a1], u2 = p[a2], u3 = p[a3];
            float e = f0 * blo(u0) + f1 * blo(u1) + f2 * blo(u2) + f3 * blo(u3);
            float o = f0 * bhi(u0) + f1 * bhi(u1) + f2 * bhi(u2) + f3 * bhi(u3);
            res[k] = pack2(e, o);
        }
    }

    // transpose through LDS: row = w (pos), 32 chunks of 4 dwords, chunk-XOR swizzle
    __shared__ uint lds[64 * 128];        // 32 KB
#pragma unroll
    for (int i = 0; i < 8; ++i) {
        int cc = cg * 8 + i;
        int sc = cc ^ (w & 7);
        *(uint4*)&lds[w * 128 + sc * 4] = *(uint4*)&res[i * 4];
    }
    __syncthreads();

    // write out: per instr, 64 lanes cover 2 rows x 512B contiguous = full lines
    int l = t & 63, wvv = t >> 6;
    size_t rowb = (size_t)(b * 4096 + h * 64);
#pragma unroll
    for (int k = 0; k < 8; ++k) {
        int p  = wvv * 16 + k * 2 + (l >> 5);
        int cc = l & 31;
        uint4 v = *(uint4*)&lds[p * 128 + ((cc ^ (p & 7)) * 4)];
        ushort* dst = vals + (rowb + p) * KD + tap * 256 + cc * 8;
        *(uint4*)dst = v;
    }
}

// ---- main GEMM: C[pos][o] = vals[pos][k] . Bt[o][k], BM=64 BN=128 BK=64
__global__ __launch_bounds__(256) void gemm_main(const ushort* __restrict__ A,
                                                 const ushort* __restrict__ Bt,
                                                 float* __restrict__ out) {
    int posBase = blockIdx.x * 64;
    int oBase   = blockIdx.y * 128;
    int t = threadIdx.x, wv = t >> 6, lane = t & 63;
    int mrow = lane & 15, quad = lane >> 4;
    int lrow = lane >> 3, lcc = lane & 7;

    __shared__ ushort lA[64 * 64];
    __shared__ ushort lB[128 * 64];

    f32x4 acc[4][2];
#pragma unroll
    for (int m = 0; m < 4; ++m)
#pragma unroll
        for (int n = 0; n < 2; ++n) acc[m][n] = {0.f, 0.f, 0.f, 0.f};

    for (int k0 = 0; k0 < KD; k0 += 64) {
#pragma unroll
        for (int s = 0; s < 2; ++s) {            // A: 8KB, 2 instr/wave
            int q = wv * 2 + s;
            int r = q * 8 + lrow;
            int gcc = lcc ^ (r & 7);
            const ushort* gp = A + (size_t)(posBase + r) * KD + k0 + gcc * 8;
            load_lds16(gp, (char*)lA + q * 1024);
        }
#pragma unroll
        for (int s = 0; s < 4; ++s) {            // B: 16KB, 4 instr/wave
            int q = wv * 4 + s;
            int r = q * 8 + lrow;
            int gcc = lcc ^ (r & 7);
            const ushort* gp = Bt + (size_t)(oBase + r) * KD + k0 + gcc * 8;
            load_lds16(gp, (char*)lB + q * 1024);
        }
        __syncthreads();
#pragma unroll
        for (int kb = 0; kb < 2; ++kb) {
            bf16x8 af[4], bf[2];
#pragma unroll
            for (int m = 0; m < 4; ++m) {
                int r = m * 16 + mrow;
                af[m] = *(const bf16x8*)&lA[r * 64 + (((kb * 4 + quad) ^ (r & 7)) * 8)];
            }
#pragma unroll
            for (int n = 0; n < 2; ++n) {
                int r = wv * 32 + n * 16 + mrow;
                bf[n] = *(const bf16x8*)&lB[r * 64 + (((kb * 4 + quad) ^ (r & 7)) * 8)];
            }
#pragma unroll
            for (int m = 0; m < 4; ++m)
#pragma unroll
                for (int n = 0; n < 2; ++n)
                    acc[m][n] = __builtin_amdgcn_mfma_f32_16x16x32_bf16(af[m], bf[n], acc[m][n], 0, 0, 0);
        }
        __syncthreads();
    }
#pragma unroll
    for (int m = 0; m < 4; ++m)
#pragma unroll
        for (int n = 0; n < 2; ++n) {
            int o   = oBase + wv * 32 + n * 16 + mrow;
            int pos = posBase + m * 16 + quad * 4;
            int b = pos >> 12, hw = pos & 4095;
            *(f32x4*)(out + ((size_t)(b * 256 + o)) * HW + hw) = acc[m][n];
        }
}

// ---- BN stats + apply ----
__global__ __launch_bounds__(256) void bn_stats(const float* __restrict__ out,
                                                const float* __restrict__ gamma,
                                                float* __restrict__ mean_s,
                                                float* __restrict__ scale_s) {
    int o = blockIdx.x;
    float s = 0.f, s2 = 0.f;
    for (int b = 0; b < 4; ++b) {
        const float4* p = (const float4*)(out + ((size_t)(b * 256 + o)) * HW);
        for (int i = threadIdx.x; i < HW / 4; i += 256) {
            float4 v = p[i];
            s  += v.x + v.y + v.z + v.w;
            s2 += v.x * v.x + v.y * v.y + v.z * v.z + v.w * v.w;
        }
    }
#pragma unroll
    for (int d = 32; d; d >>= 1) {
        s  += __shfl_down(s, d);
        s2 += __shfl_down(s2, d);
    }
    __shared__ float ws1[4], ws2[4];
    int lane = threadIdx.x & 63, wv = threadIdx.x >> 6;
    if (lane == 0) { ws1[wv] = s; ws2[wv] = s2; }
    __syncthreads();
    if (threadIdx.x == 0) {
        float S  = ws1[0] + ws1[1] + ws1[2] + ws1[3];
        float S2 = ws2[0] + ws2[1] + ws2[2] + ws2[3];
        float m  = S / 16384.f;
        float var = S2 / 16384.f - m * m;
        mean_s[o]  = m;
        scale_s[o] = gamma[o] * rsqrtf(var + 1e-5f);
    }
}

__global__ void bn_apply(float* __restrict__ out,
                         const float* __restrict__ mean_s,
                         const float* __restrict__ scale_s,
                         const float* __restrict__ beta) {
    int idx4 = blockIdx.x * 256 + threadIdx.x;   // 1,048,576 float4s
    int o = (idx4 >> 10) & 255;
    float4 v = ((const float4*)out)[idx4];
    float mu = mean_s[o], sc = scale_s[o], be = beta[o];
    v.x = fmaxf((v.x - mu) * sc + be, 0.f);
    v.y = fmaxf((v.y - mu) * sc + be, 0.f);
    v.z = fmaxf((v.z - mu) * sc + be, 0.f);
    v.w = fmaxf((v.w - mu) * sc + be, 0.f);
    ((float4*)out)[idx4] = v;
}

extern "C" void kernel_launch(void* const* d_in, const int* in_sizes, int n_in,
                              void* d_out, int out_size, void* d_ws, size_t ws_size,
                              hipStream_t stream) {
    const float* x     = (const float*)d_in[0];
    const float* w_off = (const float*)d_in[1];
    const float* b_off = (const float*)d_in[2];
    const float* w_def = (const float*)d_in[3];
    const float* gamma = (const float*)d_in[4];
    const float* beta  = (const float*)d_in[5];
    float* out = (float*)d_out;

    char* ws = (char*)d_ws;
    uint*   x2    = (uint*)ws;                          // 8,388,608 B
    ushort* vals  = (ushort*)(ws + 8388608);            // 75,497,472 B
    ushort* bt    = (ushort*)(ws + 83886080);           // 1,179,648 B
    ushort* bt0   = (ushort*)(ws + 85065728);           // 147,456 B
    float*  off   = (float*)(ws + 85213184);            // 2,097,152 B
    float*  mean_s  = (float*)(ws + 87310336);
    float*  scale_s = (float*)(ws + 87311360);

    prep_x2 <<<8192, 256, 0, stream>>>(x, x2);
    prep_bt <<<2304, 256, 0, stream>>>(w_def, bt);
    prep_bt0<<<288,  256, 0, stream>>>(w_off, bt0);
    gemm_off<<<256, 256, 0, stream>>>(x2, bt0, b_off, off);
    gather_vals<<<2304, 256, 0, stream>>>(x2, off, vals);
    gemm_main<<<dim3(256, 2), 256, 0, stream>>>(vals, bt, out);
    bn_stats<<<256, 256, 0, stream>>>(out, gamma, mean_s, scale_s);
    bn_apply<<<4096, 256, 0, stream>>>(out, mean_s, scale_s, beta);
}

// Round 4
// 175.991 us; speedup vs baseline: 2.2645x; 1.1165x over previous
//
#include <hip/hip_runtime.h>
#include <hip/hip_bf16.h>

typedef unsigned int  uint;
typedef unsigned short ushort;
typedef short bf16x8 __attribute__((ext_vector_type(8)));
typedef float f32x4  __attribute__((ext_vector_type(4)));

#define HW   4096
#define KD   2304   // 9 taps * 256 c

__device__ __forceinline__ void load_lds16(const void* g, void* l) {
    __builtin_amdgcn_global_load_lds((const __attribute__((address_space(1))) void*)g,
                                     (__attribute__((address_space(3))) void*)l, 16, 0, 0);
}
__device__ __forceinline__ float blo(uint u) { return __uint_as_float(u << 16); }
__device__ __forceinline__ float bhi(uint u) { return __uint_as_float(u & 0xffff0000u); }
__device__ __forceinline__ uint pack2(float e, float o) {
    __hip_bfloat16 he = __float2bfloat16(e), ho = __float2bfloat16(o);
    return (uint)(*(ushort*)&he) | ((uint)(*(ushort*)&ho) << 16);
}

// ---- x -> bf16 channel-pair-interleaved: x2[(b*128+cp)*4096 + a] = {c=2cp, c=2cp+1}
__global__ void prep_x2(const float* __restrict__ x, uint* __restrict__ x2) {
    int idx = blockIdx.x * 256 + threadIdx.x;      // 2,097,152
    int a  = idx & 4095;
    int cp = (idx >> 12) & 127;
    int b  = idx >> 19;
    const float* p = x + ((size_t)(b * 256 + 2 * cp)) * HW + a;
    x2[idx] = pack2(p[0], p[HW]);
}

// ---- w_def -> Bt[o*2304 + tap*256 + c]
__global__ void prep_bt(const float* __restrict__ w_def, ushort* __restrict__ bt) {
    int idx = blockIdx.x * 256 + threadIdx.x;      // 589,824
    int c   = idx & 255;
    int tap = (idx >> 8) % 9;
    int o   = idx / KD;
    __hip_bfloat16 h = __float2bfloat16(w_def[(o * 256 + c) * 9 + tap]);
    bt[idx] = *(ushort*)&h;
}

// ---- w_off -> Bt0[j*2304 + tap*256 + c], rows 18..31 zero
__global__ void prep_bt0(const float* __restrict__ w_off, ushort* __restrict__ bt0) {
    int idx = blockIdx.x * 256 + threadIdx.x;      // 73,728
    int c   = idx & 255;
    int tap = (idx >> 8) % 9;
    int j   = idx / KD;
    float v = (j < 18) ? w_off[(j * 256 + c) * 9 + tap] : 0.f;
    __hip_bfloat16 h = __float2bfloat16(v);
    bt0[idx] = *(ushort*)&h;
}

// ---- fused offset conv: direct implicit GEMM from x2, no im2col ----
__global__ __launch_bounds__(256) void gemm_off(const uint* __restrict__ x2,
                                                const ushort* __restrict__ bt0,
                                                const float* __restrict__ b_off,
                                                float* __restrict__ off) {
    int id = blockIdx.x;
    int xcd = id & 7;
    int b = xcd >> 1, h = (xcd & 1) * 32 + (id >> 3);
    int t = threadIdx.x, wv = t >> 6, lane = t & 63;
    int mrow = lane & 15, quad = lane >> 4;

    __shared__ uint   lX[3 * 32 * 64];     // [dy][cp][w] dwords, 24 KB
    __shared__ ushort lB[32 * 576];        // [o][72 chunks of 8, XOR-swizzled], 36 KB

    f32x4 acc[2];
    acc[0] = {0.f, 0.f, 0.f, 0.f};
    acc[1] = {0.f, 0.f, 0.f, 0.f};

    for (int cb = 0; cb < 4; ++cb) {
#pragma unroll
        for (int s = 0; s < 6; ++s) {
            int q  = s * 4 + wv;
            int dy = q >> 3;
            int y  = h + dy - 1;
            int dl = (q & 7) * 256 + lane * 4;
            int cp = dl >> 6, w4 = dl & 63;
            uint* dst = &lX[q * 256 + lane * 4];
            if ((unsigned)y < 64u) {
                const uint* src = x2 + ((size_t)(b * 128 + cb * 32 + cp)) * HW + y * 64 + w4;
                load_lds16(src, &lX[q * 256]);
            } else {
                uint4 z = {0u, 0u, 0u, 0u};
                *(uint4*)dst = z;
            }
        }
#pragma unroll
        for (int s = 0; s < 9; ++s) {
            int q = s * 4 + wv;
            int e = q * 512 + lane * 8;
            int o  = e / 576;
            int r  = e - o * 576;
            int chp = r >> 3;
            int ch  = chp ^ (o & 7);
            int tap = ch >> 3, k8 = ch & 7;
            const ushort* src = bt0 + (size_t)o * KD + tap * 256 + cb * 64 + k8 * 8;
            load_lds16(src, &lB[q * 512]);
        }
        __syncthreads();

#pragma unroll
        for (int tap = 0; tap < 9; ++tap) {
            int dy = tap / 3, dx = tap % 3;
            int xx = wv * 16 + mrow + dx - 1;
            bool vx = (unsigned)xx < 64u;
#pragma unroll
            for (int kb = 0; kb < 2; ++kb) {
                int cp0 = kb * 16 + quad * 4;
                uint ad[4];
#pragma unroll
                for (int i = 0; i < 4; ++i)
                    ad[i] = vx ? lX[(dy * 32 + cp0 + i) * 64 + xx] : 0u;
                bf16x8 af = *(bf16x8*)ad;
#pragma unroll
                for (int n = 0; n < 2; ++n) {
                    int o = n * 16 + mrow;
                    int chs = (tap * 8 + (((kb * 4 + quad)) ^ (o & 7)));
                    bf16x8 bfr = *(const bf16x8*)&lB[o * 576 + chs * 8];
                    acc[n] = __builtin_amdgcn_mfma_f32_16x16x32_bf16(af, bfr, acc[n], 0, 0, 0);
                }
            }
        }
        __syncthreads();
    }
#pragma unroll
    for (int n = 0; n < 2; ++n) {
        int o = n * 16 + mrow;
        float bias = (o < 18) ? b_off[o] : 0.f;
        f32x4 v = acc[n];
        v.x += bias; v.y += bias; v.z += bias; v.w += bias;
        int wpos = wv * 16 + quad * 4;
        *(f32x4*)(off + ((size_t)(b * 32 + o)) * HW + h * 64 + wpos) = v;
    }
}

// ---- fused gather + main GEMM + BN-stats accumulation ----
// One (b,h) 64-pos tile per block. BM=64, BN=256, K=2304 in 36 slices of 64.
__global__ __launch_bounds__(512) void fused_main(const uint* __restrict__ x2,
                                                  const ushort* __restrict__ bt,
                                                  const float* __restrict__ off,
                                                  float* __restrict__ out,
                                                  float* __restrict__ stats) {
    int id = blockIdx.x;                      // 256 blocks
    int xcd = id & 7;
    int b = xcd >> 1, h = (xcd & 1) * 32 + (id >> 3);
    int t = threadIdx.x;
    int wv = t >> 6, lane = t & 63;
    int mrow = lane & 15, quad = lane >> 4;
    int w  = t & 63;                          // pos within tile (gather role)
    int cq = (t >> 6) & 7;                    // channel-chunk (gather role)

    __shared__ int    sAc[4][9][64];          // corner plane offsets, 9 KB
    __shared__ float  sWc[4][9][64];          // corner weights, 9 KB
    __shared__ ushort lA[2][64 * 64];         // 2 x 8 KB
    __shared__ ushort lB[2][256 * 64];        // 2 x 32 KB

    // ---- per-tile coords for all 9 taps ----
    for (int i = t; i < 576; i += 512) {
        int tap = i >> 6, ww = i & 63;
        int hw = h * 64 + ww;
        float oy = off[((size_t)(b * 32 + 2 * tap)) * HW + hw];
        float ox = off[((size_t)(b * 32 + 2 * tap + 1)) * HW + hw];
        float py = oy + (float)(tap / 3 + h - 1);
        float px = ox + (float)(tap % 3 + ww - 1);
        float y0f = floorf(py), x0f = floorf(px);
        float wy1 = py - y0f, wx1 = px - x0f;
        float wy0 = 1.f - wy1, wx0 = 1.f - wx1;
        bool vy0 = (y0f >= 0.f) && (y0f <= 63.f);
        bool vy1 = (y0f >= -1.f) && (y0f <= 62.f);
        bool vx0 = (x0f >= 0.f) && (x0f <= 63.f);
        bool vx1 = (x0f >= -1.f) && (x0f <= 62.f);
        int iy0 = min(max((int)y0f, 0), 63),  iy1 = min(max((int)y0f + 1, 0), 63);
        int ix0 = min(max((int)x0f, 0), 63),  ix1 = min(max((int)x0f + 1, 0), 63);
        sAc[0][tap][ww] = iy0 * 64 + ix0;
        sAc[1][tap][ww] = iy0 * 64 + ix1;
        sAc[2][tap][ww] = iy1 * 64 + ix0;
        sAc[3][tap][ww] = iy1 * 64 + ix1;
        sWc[0][tap][ww] = wy0 * wx0 * (float)(vy0 && vx0);
        sWc[1][tap][ww] = wy0 * wx1 * (float)(vy0 && vx1);
        sWc[2][tap][ww] = wy1 * wx0 * (float)(vy1 && vx0);
        sWc[3][tap][ww] = wy1 * wx1 * (float)(vy1 && vx1);
    }
    __syncthreads();

    f32x4 acc[4][2];
#pragma unroll
    for (int m = 0; m < 4; ++m)
#pragma unroll
        for (int n = 0; n < 2; ++n) acc[m][n] = {0.f, 0.f, 0.f, 0.f};

    const uint* xb = x2 + (size_t)(b * 128) * HW;

    // stage helper bodies inlined; slice s: tap = s>>2, cb = s&3
    // ---- prologue: stage slice 0 into buf 0 ----
    {
        int tap = 0, cb = 0;
        int a0 = sAc[0][tap][w], a1 = sAc[1][tap][w], a2 = sAc[2][tap][w], a3 = sAc[3][tap][w];
        float f0 = sWc[0][tap][w], f1 = sWc[1][tap][w], f2 = sWc[2][tap][w], f3 = sWc[3][tap][w];
        const uint* xp = xb + (size_t)(cb * 32 + cq * 4) * HW;
        uint r[4];
#pragma unroll
        for (int j = 0; j < 4; ++j) {
            const uint* p = xp + (size_t)j * HW;
            uint u0 = p[a0], u1 = p[a1], u2 = p[a2], u3 = p[a3];
            float e = f0 * blo(u0) + f1 * blo(u1) + f2 * blo(u2) + f3 * blo(u3);
            float o = f0 * bhi(u0) + f1 * bhi(u1) + f2 * bhi(u2) + f3 * bhi(u3);
            r[j] = pack2(e, o);
        }
        uint4 g = {r[0], r[1], r[2], r[3]};
        *(uint4*)&lA[0][w * 64 + ((cq ^ (w & 7)) * 8)] = g;
#pragma unroll
        for (int s2 = 0; s2 < 4; ++s2) {
            int e = s2 * 512 + t;
            int o = e >> 3, pp = e & 7;
            int k8 = pp ^ (o & 7);
            const ushort* src = bt + (size_t)o * KD + tap * 256 + cb * 64 + k8 * 8;
            load_lds16(src, &lB[0][(e & ~63) * 8]);
        }
    }

    int p = 0;
    for (int s = 0; s < 36; ++s) {
        __syncthreads();                       // slice s staged & visible in buf p
        bool more = (s + 1) < 36;
        uint4 g;
        if (more) {
            int tap = (s + 1) >> 2, cb = (s + 1) & 3;
            int a0 = sAc[0][tap][w], a1 = sAc[1][tap][w], a2 = sAc[2][tap][w], a3 = sAc[3][tap][w];
            float f0 = sWc[0][tap][w], f1 = sWc[1][tap][w], f2 = sWc[2][tap][w], f3 = sWc[3][tap][w];
            const uint* xp = xb + (size_t)(cb * 32 + cq * 4) * HW;
            uint r[4];
#pragma unroll
            for (int j = 0; j < 4; ++j) {
                const uint* pq = xp + (size_t)j * HW;
                uint u0 = pq[a0], u1 = pq[a1], u2 = pq[a2], u3 = pq[a3];
                float e = f0 * blo(u0) + f1 * blo(u1) + f2 * blo(u2) + f3 * blo(u3);
                float o = f0 * bhi(u0) + f1 * bhi(u1) + f2 * bhi(u2) + f3 * bhi(u3);
                r[j] = pack2(e, o);
            }
            g = {r[0], r[1], r[2], r[3]};
#pragma unroll
            for (int s2 = 0; s2 < 4; ++s2) {
                int e = s2 * 512 + t;
                int o = e >> 3, pp = e & 7;
                int k8 = pp ^ (o & 7);
                const ushort* src = bt + (size_t)o * KD + tap * 256 + cb * 64 + k8 * 8;
                load_lds16(src, &lB[p ^ 1][(e & ~63) * 8]);
            }
        }
        // ---- MFMA on buf p ----
#pragma unroll
        for (int kb = 0; kb < 2; ++kb) {
            bf16x8 af[4];
#pragma unroll
            for (int m = 0; m < 4; ++m) {
                int r = m * 16 + mrow;
                af[m] = *(const bf16x8*)&lA[p][r * 64 + (((kb * 4 + quad) ^ (r & 7)) * 8)];
            }
#pragma unroll
            for (int n = 0; n < 2; ++n) {
                int r = wv * 32 + n * 16 + mrow;
                bf16x8 bfr = *(const bf16x8*)&lB[p][r * 64 + (((kb * 4 + quad) ^ (r & 7)) * 8)];
#pragma unroll
                for (int m = 0; m < 4; ++m)
                    acc[m][n] = __builtin_amdgcn_mfma_f32_16x16x32_bf16(af[m], bfr, acc[m][n], 0, 0, 0);
            }
        }
        if (more)
            *(uint4*)&lA[p ^ 1][w * 64 + ((cq ^ (w & 7)) * 8)] = g;
        p ^= 1;
    }

    // ---- epilogue: store + BN stats ----
#pragma unroll
    for (int n = 0; n < 2; ++n) {
        int o = wv * 32 + n * 16 + mrow;
        float ss = 0.f, qq = 0.f;
#pragma unroll
        for (int m = 0; m < 4; ++m) {
            int pos = m * 16 + quad * 4;
            f32x4 v = acc[m][n];
            *(f32x4*)(out + ((size_t)(b * 256 + o)) * HW + h * 64 + pos) = v;
            ss += v.x + v.y + v.z + v.w;
            qq += v.x * v.x + v.y * v.y + v.z * v.z + v.w * v.w;
        }
        ss += __shfl_xor(ss, 16); ss += __shfl_xor(ss, 32);
        qq += __shfl_xor(qq, 16); qq += __shfl_xor(qq, 32);
        if (quad == 0) {
            atomicAdd(&stats[o], ss);
            atomicAdd(&stats[512 + o], qq);
        }
    }
}

// ---- BN finalize + apply ----
__global__ void bn_finalize(const float* __restrict__ stats,
                            const float* __restrict__ gamma,
                            float* __restrict__ ms) {
    int o = threadIdx.x;                      // 256
    float S = stats[o], S2 = stats[512 + o];
    float m  = S / 16384.f;
    float var = S2 / 16384.f - m * m;
    ms[o]       = m;
    ms[256 + o] = gamma[o] * rsqrtf(var + 1e-5f);
}

__global__ void bn_apply(float* __restrict__ out,
                         const float* __restrict__ ms,
                         const float* __restrict__ beta) {
    int idx4 = blockIdx.x * 256 + threadIdx.x;   // 1,048,576 float4s
    int o = (idx4 >> 10) & 255;
    float4 v = ((const float4*)out)[idx4];
    float mu = ms[o], sc = ms[256 + o], be = beta[o];
    v.x = fmaxf((v.x - mu) * sc + be, 0.f);
    v.y = fmaxf((v.y - mu) * sc + be, 0.f);
    v.z = fmaxf((v.z - mu) * sc + be, 0.f);
    v.w = fmaxf((v.w - mu) * sc + be, 0.f);
    ((float4*)out)[idx4] = v;
}

extern "C" void kernel_launch(void* const* d_in, const int* in_sizes, int n_in,
                              void* d_out, int out_size, void* d_ws, size_t ws_size,
                              hipStream_t stream) {
    const float* x     = (const float*)d_in[0];
    const float* w_off = (const float*)d_in[1];
    const float* b_off = (const float*)d_in[2];
    const float* w_def = (const float*)d_in[3];
    const float* gamma = (const float*)d_in[4];
    const float* beta  = (const float*)d_in[5];
    float* out = (float*)d_out;

    char* ws = (char*)d_ws;
    uint*   x2    = (uint*)ws;                          // 8,388,608 B
    ushort* bt    = (ushort*)(ws + 8388608);            // 1,179,648 B
    ushort* bt0   = (ushort*)(ws + 9568256);            // 147,456 B
    float*  off   = (float*)(ws + 9715712);             // 2,097,152 B
    float*  stats = (float*)(ws + 11812864);            // 4,096 B
    float*  ms    = (float*)(ws + 11816960);            // 2,048 B

    hipMemsetAsync(stats, 0, 4096, stream);
    prep_x2 <<<8192, 256, 0, stream>>>(x, x2);
    prep_bt <<<2304, 256, 0, stream>>>(w_def, bt);
    prep_bt0<<<288,  256, 0, stream>>>(w_off, bt0);
    gemm_off<<<256, 256, 0, stream>>>(x2, bt0, b_off, off);
    fused_main<<<256, 512, 0, stream>>>(x2, bt, off, out, stats);
    bn_finalize<<<1, 256, 0, stream>>>(stats, gamma, ms);
    bn_apply<<<4096, 256, 0, stream>>>(out, ms, beta);
}